// Round 1
// baseline (266.330 us; speedup 1.0000x reference)
//
#include <hip/hip_runtime.h>
#include <hip/hip_bf16.h>

// Problem constants
#define NB   64
#define NCDD 5
#define NHIS 100
#define NT   30
#define NL   3
#define ND   256
#define NK   10
#define TLD  23040          // NT*NL*ND
#define THRESH 0.1f

// ---------------------------------------------------------------------------
// Kernel 1: Y[r][d] = l2norm_row( X[r] @ W^T + b )  for a tile of 16 rows.
// Block = 256 threads (one per output column d). X tile staged in LDS;
// each thread streams its own W row (L2-resident, 256 KB total).
// ---------------------------------------------------------------------------
__global__ void proj_norm_kernel(const float* __restrict__ X,
                                 const float* __restrict__ W,
                                 const float* __restrict__ bvec,
                                 float* __restrict__ Y)
{
    __shared__ float xs[16][256];
    __shared__ float red[4][16];
    const int r0  = blockIdx.x * 16;
    const int tid = threadIdx.x;

    // Stage 16 input rows (coalesced float4)
    for (int i = tid; i < 16 * 64; i += 256) {
        const int row = i >> 6, c4 = i & 63;
        ((float4*)&xs[row][0])[c4] =
            ((const float4*)(X + (size_t)(r0 + row) * ND))[c4];
    }
    __syncthreads();

    const int d = tid;
    const float bias = bvec[d];
    float acc[16];
#pragma unroll
    for (int r = 0; r < 16; ++r) acc[r] = bias;

    const float* wrow = W + (size_t)d * ND;
    for (int k = 0; k < ND; k += 4) {
        const float4 w4 = *(const float4*)(wrow + k);
#pragma unroll
        for (int r = 0; r < 16; ++r) {
            const float4 x4 = *(const float4*)&xs[r][k];   // LDS broadcast
            acc[r] += w4.x * x4.x + w4.y * x4.y + w4.z * x4.z + w4.w * x4.w;
        }
    }

    // Row-wise sum of squares across the 256 threads
    const int wave = tid >> 6, lane = tid & 63;
#pragma unroll
    for (int r = 0; r < 16; ++r) {
        float v = acc[r] * acc[r];
        for (int off = 32; off; off >>= 1) v += __shfl_xor(v, off);
        if (lane == 0) red[wave][r] = v;
    }
    __syncthreads();

#pragma unroll
    for (int r = 0; r < 16; ++r) {
        const float s = red[0][r] + red[1][r] + red[2][r] + red[3][r];
        const float scale = 1.0f / fmaxf(sqrtf(s), 1e-12f);
        Y[(size_t)(r0 + r) * ND + d] = acc[r] * scale;
    }
}

// ---------------------------------------------------------------------------
// Kernel 2: per (b,c): attn[h] = dot(cdd_p[b,c], his_p[b,h]); exact top-10
// with lax.top_k semantics (descending, stable lowest-index ties).
// Grid = 320 blocks, 256 threads (4 waves; each wave owns h = wave, wave+4,...)
// ---------------------------------------------------------------------------
__global__ void attn_topk_kernel(const float* __restrict__ cdd_p,
                                 const float* __restrict__ his_p,
                                 float* __restrict__ out_idx_f,
                                 int* __restrict__ ws_idx,
                                 float* __restrict__ ws_w)
{
    __shared__ float cvec[ND];
    __shared__ float attn[NHIS];
    const int bc  = blockIdx.x;            // b*NCDD + c
    const int b   = bc / NCDD;
    const int tid = threadIdx.x;
    const int wave = tid >> 6, lane = tid & 63;

    cvec[tid] = cdd_p[(size_t)bc * ND + tid];
    __syncthreads();

    const float4 c4 = ((const float4*)cvec)[lane];
    for (int h = wave; h < NHIS; h += 4) {
        const float4 h4 =
            ((const float4*)(his_p + ((size_t)b * NHIS + h) * ND))[lane];
        float v = c4.x * h4.x + c4.y * h4.y + c4.z * h4.z + c4.w * h4.w;
        for (int off = 32; off; off >>= 1) v += __shfl_xor(v, off);
        if (lane == 0) attn[h] = v;
    }
    __syncthreads();

    if (tid == 0) {
        unsigned long long used0 = 0ull, used1 = 0ull;
        for (int k = 0; k < NK; ++k) {
            float best = -__builtin_inff();
            int bi = 0;
            for (int h = 0; h < NHIS; ++h) {
                const bool u = (h < 64) ? ((used0 >> h) & 1ull)
                                        : ((used1 >> (h - 64)) & 1ull);
                if (u) continue;
                const float v = attn[h];
                if (v > best) { best = v; bi = h; }   // strict > => lowest idx on tie
            }
            if (bi < 64) used0 |= (1ull << bi); else used1 |= (1ull << (bi - 64));
            const float w = (best < THRESH) ? 0.0f : best;
            const int g = bc * NK + k;
            ws_idx[g] = bi;
            ws_w[g]   = w;
            out_idx_f[g] = (float)bi;      // idx output written as float values
        }
    }
}

// ---------------------------------------------------------------------------
// Kernel 3: gather + scale. One block per (b,c,k): copy his_embedding row
// (23040 f32) * w. Coalesced float4 in and out. HBM-bound (~590 MB total).
// ---------------------------------------------------------------------------
__global__ void gather_kernel(const float* __restrict__ his_emb,
                              const int* __restrict__ ws_idx,
                              const float* __restrict__ ws_w,
                              float* __restrict__ out)
{
    const int g = blockIdx.x;              // (b*NCDD + c)*NK + k
    const int b = g / (NCDD * NK);
    const int idx = ws_idx[g];
    const float w = ws_w[g];

    const float4* __restrict__ src =
        (const float4*)(his_emb + ((size_t)b * NHIS + idx) * TLD);
    float4* __restrict__ dst = (float4*)(out + (size_t)g * TLD);

    for (int i = threadIdx.x; i < TLD / 4; i += 256) {
        float4 v = src[i];
        v.x *= w; v.y *= w; v.z *= w; v.w *= w;
        dst[i] = v;
    }
}

// ---------------------------------------------------------------------------
extern "C" void kernel_launch(void* const* d_in, const int* in_sizes, int n_in,
                              void* d_out, int out_size, void* d_ws, size_t ws_size,
                              hipStream_t stream)
{
    const float* cdd_repr = (const float*)d_in[0];   // (64,5,256)
    const float* his_repr = (const float*)d_in[1];   // (64,100,256)
    const float* his_emb  = (const float*)d_in[2];   // (64,100,30,3,256)
    const float* W_sel    = (const float*)d_in[3];   // (256,256)
    const float* b_sel    = (const float*)d_in[4];   // (256,)
    float* out = (float*)d_out;

    // Workspace layout (≈6.9 MB)
    char* ws = (char*)d_ws;
    float* his_p = (float*)(ws);                     // 6400*256*4 = 6,553,600 B
    float* cdd_p = (float*)(ws + 6553600);           //  320*256*4 =   327,680 B
    int*   idx_i = (int*)  (ws + 6881280);           // 3200*4
    float* w_w   = (float*)(ws + 6894080);           // 3200*4

    // Output layout: his_activated [73,728,000] then idx [3200] (as floats)
    float* out_idx_f = out + (size_t)NB * NCDD * NK * TLD;

    proj_norm_kernel<<<(NB * NHIS) / 16, 256, 0, stream>>>(his_repr, W_sel, b_sel, his_p);
    proj_norm_kernel<<<(NB * NCDD) / 16, 256, 0, stream>>>(cdd_repr, W_sel, b_sel, cdd_p);
    attn_topk_kernel<<<NB * NCDD, 256, 0, stream>>>(cdd_p, his_p, out_idx_f, idx_i, w_w);
    gather_kernel<<<NB * NCDD * NK, 256, 0, stream>>>(his_emb, idx_i, w_w, out);
}

// Round 2
// 179.334 us; speedup vs baseline: 1.4851x; 1.4851x over previous
//
#include <hip/hip_runtime.h>
#include <hip/hip_bf16.h>

// Problem constants
#define NB   64
#define NCDD 5
#define NHIS 100
#define ND   256
#define NK   10
#define TLD  23040          // T*L*D = 30*3*256
#define THRESH 0.1f
#define NEG_INF (-3.402823466e38f)

typedef float f32x4 __attribute__((ext_vector_type(4)));

// ---------------------------------------------------------------------------
// Kernel 1: his projection+norm, 16 rows per block (unchanged from R1 — VALU
// bound at ~full f32 FMA rate, LDS reads are same-address broadcasts).
// ---------------------------------------------------------------------------
__global__ __launch_bounds__(256) void proj_norm_kernel(
    const float* __restrict__ X,
    const float* __restrict__ W,
    const float* __restrict__ bvec,
    float* __restrict__ Y)
{
    __shared__ float xs[16][256];
    __shared__ float red[4][16];
    const int r0  = blockIdx.x * 16;
    const int tid = threadIdx.x;

    for (int i = tid; i < 16 * 64; i += 256) {
        const int row = i >> 6, c4 = i & 63;
        ((float4*)&xs[row][0])[c4] =
            ((const float4*)(X + (size_t)(r0 + row) * ND))[c4];
    }
    __syncthreads();

    const int d = tid;
    const float bias = bvec[d];
    float acc[16];
#pragma unroll
    for (int r = 0; r < 16; ++r) acc[r] = bias;

    const float* wrow = W + (size_t)d * ND;
    for (int k = 0; k < ND; k += 4) {
        const float4 w4 = *(const float4*)(wrow + k);
#pragma unroll
        for (int r = 0; r < 16; ++r) {
            const float4 x4 = *(const float4*)&xs[r][k];   // LDS broadcast
            acc[r] += w4.x * x4.x + w4.y * x4.y + w4.z * x4.z + w4.w * x4.w;
        }
    }

    const int wave = tid >> 6, lane = tid & 63;
#pragma unroll
    for (int r = 0; r < 16; ++r) {
        float v = acc[r] * acc[r];
        for (int off = 32; off; off >>= 1) v += __shfl_xor(v, off);
        if (lane == 0) red[wave][r] = v;
    }
    __syncthreads();

#pragma unroll
    for (int r = 0; r < 16; ++r) {
        const float s = red[0][r] + red[1][r] + red[2][r] + red[3][r];
        const float scale = 1.0f / fmaxf(sqrtf(s), 1e-12f);
        Y[(size_t)(r0 + r) * ND + d] = acc[r] * scale;
    }
}

// ---------------------------------------------------------------------------
// Kernel 2 (fused): per (b,c) block — cdd projection+norm, attn over 100 h,
// wave-parallel exact top-10 (lax.top_k tie semantics: descending, lowest
// index on ties).
// ---------------------------------------------------------------------------
__global__ __launch_bounds__(256) void cdd_attn_topk_kernel(
    const float* __restrict__ cdd_repr,
    const float* __restrict__ W,
    const float* __restrict__ bvec,
    const float* __restrict__ his_p,
    float* __restrict__ out_idx_f,
    int* __restrict__ ws_idx,
    float* __restrict__ ws_w)
{
    __shared__ float xs[ND];
    __shared__ float cvec[ND];
    __shared__ float attn_s[NHIS];
    __shared__ float red[4];
    const int bc  = blockIdx.x;            // b*NCDD + c
    const int b   = bc / NCDD;
    const int tid = threadIdx.x;
    const int wave = tid >> 6, lane = tid & 63;

    xs[tid] = cdd_repr[(size_t)bc * ND + tid];
    __syncthreads();

    // Projection: acc[d] = b[d] + dot(xs, W[d,:])
    float acc = bvec[tid];
    const float* wrow = W + (size_t)tid * ND;
    for (int k = 0; k < ND; k += 4) {
        const float4 w4 = *(const float4*)(wrow + k);
        const float4 x4 = *(const float4*)&xs[k];          // LDS broadcast
        acc += w4.x * x4.x + w4.y * x4.y + w4.z * x4.z + w4.w * x4.w;
    }
    // L2-normalize across the 256 outputs
    float ss = acc * acc;
    for (int off = 32; off; off >>= 1) ss += __shfl_xor(ss, off);
    if (lane == 0) red[wave] = ss;
    __syncthreads();
    const float s = red[0] + red[1] + red[2] + red[3];
    const float scale = 1.0f / fmaxf(sqrtf(s), 1e-12f);
    cvec[tid] = acc * scale;
    __syncthreads();

    // attn[h] = dot(cvec, his_p[b,h,:])
    const float4 c4 = ((const float4*)cvec)[lane];
    for (int h = wave; h < NHIS; h += 4) {
        const float4 h4 =
            ((const float4*)(his_p + ((size_t)b * NHIS + h) * ND))[lane];
        float v = c4.x * h4.x + c4.y * h4.y + c4.z * h4.z + c4.w * h4.w;
        for (int off = 32; off; off >>= 1) v += __shfl_xor(v, off);
        if (lane == 0) attn_s[h] = v;
    }
    __syncthreads();

    // Wave-parallel top-10 (wave 0): lane owns h=lane and h=lane+64
    if (wave == 0) {
        float v0 = attn_s[lane];
        float v1 = (lane + 64 < NHIS) ? attn_s[lane + 64] : NEG_INF;
#pragma unroll
        for (int k = 0; k < NK; ++k) {
            float lv; int li;
            if (v1 > v0) { lv = v1; li = lane + 64; }
            else         { lv = v0; li = lane; }            // tie -> lower idx
            for (int off = 1; off < 64; off <<= 1) {
                const float ov = __shfl_xor(lv, off);
                const int   oi = __shfl_xor(li, off);
                if (ov > lv || (ov == lv && oi < li)) { lv = ov; li = oi; }
            }
            if (lane == 0) {
                const float w = (lv < THRESH) ? 0.0f : lv;
                const int g = bc * NK + k;
                ws_idx[g] = li;
                ws_w[g]   = w;
                out_idx_f[g] = (float)li;
            }
            if (li == lane)            v0 = NEG_INF;
            else if (li == lane + 64)  v1 = NEG_INF;
        }
    }
}

// ---------------------------------------------------------------------------
// Kernel 3: gather + scale. One block per (b,c,k); 23040 floats = 5760 f32x4
// = 22 full iterations + half-wave tail. Nontemporal stores (write-once).
// ---------------------------------------------------------------------------
__global__ __launch_bounds__(256) void gather_kernel(
    const float* __restrict__ his_emb,
    const int* __restrict__ ws_idx,
    const float* __restrict__ ws_w,
    float* __restrict__ out)
{
    const int g = blockIdx.x;              // (b*NCDD + c)*NK + k
    const int b = g / (NCDD * NK);
    const int idx = ws_idx[g];
    const float w = ws_w[g];
    const int tid = threadIdx.x;

    const f32x4* __restrict__ src =
        (const f32x4*)(his_emb + ((size_t)b * NHIS + idx) * TLD);
    f32x4* __restrict__ dst = (f32x4*)(out + (size_t)g * TLD);

#pragma unroll 4
    for (int it = 0; it < 22; ++it) {
        const int i = tid + it * 256;
        f32x4 v = src[i];
        v *= w;
        __builtin_nontemporal_store(v, dst + i);
    }
    if (tid < 128) {
        const int i = 22 * 256 + tid;      // 5632..5759
        f32x4 v = src[i];
        v *= w;
        __builtin_nontemporal_store(v, dst + i);
    }
}

// ---------------------------------------------------------------------------
extern "C" void kernel_launch(void* const* d_in, const int* in_sizes, int n_in,
                              void* d_out, int out_size, void* d_ws, size_t ws_size,
                              hipStream_t stream)
{
    const float* cdd_repr = (const float*)d_in[0];   // (64,5,256)
    const float* his_repr = (const float*)d_in[1];   // (64,100,256)
    const float* his_emb  = (const float*)d_in[2];   // (64,100,30,3,256)
    const float* W_sel    = (const float*)d_in[3];   // (256,256)
    const float* b_sel    = (const float*)d_in[4];   // (256,)
    float* out = (float*)d_out;

    // Workspace layout
    char* ws = (char*)d_ws;
    float* his_p = (float*)(ws);                     // 6400*256*4 = 6,553,600 B
    int*   idx_i = (int*)  (ws + 6553600);           // 3200*4
    float* w_w   = (float*)(ws + 6566400);           // 3200*4

    // Output: his_activated [73,728,000] then idx [3200] (as float values)
    float* out_idx_f = out + (size_t)NB * NCDD * NK * TLD;

    proj_norm_kernel<<<(NB * NHIS) / 16, 256, 0, stream>>>(his_repr, W_sel, b_sel, his_p);
    cdd_attn_topk_kernel<<<NB * NCDD, 256, 0, stream>>>(cdd_repr, W_sel, b_sel,
                                                        his_p, out_idx_f, idx_i, w_w);
    gather_kernel<<<NB * NCDD * NK, 256, 0, stream>>>(his_emb, idx_i, w_w, out);
}

// Round 3
// 179.215 us; speedup vs baseline: 1.4861x; 1.0007x over previous
//
#include <hip/hip_runtime.h>
#include <hip/hip_bf16.h>

// Problem constants
#define NB   64
#define NCDD 5
#define NHIS 100
#define ND   256
#define NK   10
#define TLD  23040          // T*L*D = 30*3*256
#define THRESH 0.1f
#define NEG_INF (-3.402823466e38f)

typedef float f32x4 __attribute__((ext_vector_type(4)));

// ---------------------------------------------------------------------------
// Kernel 1: his projection+norm, 16 rows per block.
// X values are lane-uniform -> load straight from global with uniform
// addresses (compiler emits s_load on the scalar pipe; v_fma takes the SGPR
// operand). No LDS staging => kernel is VALU-bound, not LDS-issue-bound.
// ---------------------------------------------------------------------------
__global__ __launch_bounds__(256) void proj_norm_kernel(
    const float* __restrict__ X,
    const float* __restrict__ W,
    const float* __restrict__ bvec,
    float* __restrict__ Y)
{
    __shared__ float red[4][16];
    const int r0  = blockIdx.x * 16;
    const int tid = threadIdx.x;

    const float bias = bvec[tid];
    float acc[16];
#pragma unroll
    for (int r = 0; r < 16; ++r) acc[r] = bias;

    const float* wrow = W + (size_t)tid * ND;
    for (int k = 0; k < ND; k += 4) {
        const float4 w4 = *(const float4*)(wrow + k);
#pragma unroll
        for (int r = 0; r < 16; ++r) {
            // uniform address (no threadIdx) -> scalar load, broadcast via SGPR
            const float4 x4 = *(const float4*)(X + (size_t)(r0 + r) * ND + k);
            acc[r] += w4.x * x4.x + w4.y * x4.y + w4.z * x4.z + w4.w * x4.w;
        }
    }

    const int wave = tid >> 6, lane = tid & 63;
#pragma unroll
    for (int r = 0; r < 16; ++r) {
        float v = acc[r] * acc[r];
        for (int off = 32; off; off >>= 1) v += __shfl_xor(v, off);
        if (lane == 0) red[wave][r] = v;
    }
    __syncthreads();

#pragma unroll
    for (int r = 0; r < 16; ++r) {
        const float s = red[0][r] + red[1][r] + red[2][r] + red[3][r];
        const float scale = 1.0f / fmaxf(sqrtf(s), 1e-12f);
        Y[(size_t)(r0 + r) * ND + tid] = acc[r] * scale;
    }
}

// ---------------------------------------------------------------------------
// Kernel 2 (fused): per (b,c) block — cdd projection+norm (scalar-load X),
// attn over 100 h, wave-parallel exact top-10 (lax.top_k tie semantics).
// ---------------------------------------------------------------------------
__global__ __launch_bounds__(256) void cdd_attn_topk_kernel(
    const float* __restrict__ cdd_repr,
    const float* __restrict__ W,
    const float* __restrict__ bvec,
    const float* __restrict__ his_p,
    float* __restrict__ out_idx_f,
    int* __restrict__ ws_idx,
    float* __restrict__ ws_w)
{
    __shared__ float cvec[ND];
    __shared__ float attn_s[NHIS];
    __shared__ float red[4];
    const int bc  = blockIdx.x;            // b*NCDD + c
    const int b   = bc / NCDD;
    const int tid = threadIdx.x;
    const int wave = tid >> 6, lane = tid & 63;

    // Projection: acc = b[tid] + dot(cdd_row, W[tid,:]); cdd row via scalar loads
    float acc = bvec[tid];
    const float* wrow = W + (size_t)tid * ND;
    const float* xrow = cdd_repr + (size_t)bc * ND;
    for (int k = 0; k < ND; k += 4) {
        const float4 w4 = *(const float4*)(wrow + k);
        const float4 x4 = *(const float4*)(xrow + k);   // uniform -> s_load
        acc += w4.x * x4.x + w4.y * x4.y + w4.z * x4.z + w4.w * x4.w;
    }
    float ss = acc * acc;
    for (int off = 32; off; off >>= 1) ss += __shfl_xor(ss, off);
    if (lane == 0) red[wave] = ss;
    __syncthreads();
    const float s = red[0] + red[1] + red[2] + red[3];
    const float scale = 1.0f / fmaxf(sqrtf(s), 1e-12f);
    cvec[tid] = acc * scale;
    __syncthreads();

    // attn[h] = dot(cvec, his_p[b,h,:])
    const float4 c4 = ((const float4*)cvec)[lane];
    for (int h = wave; h < NHIS; h += 4) {
        const float4 h4 =
            ((const float4*)(his_p + ((size_t)b * NHIS + h) * ND))[lane];
        float v = c4.x * h4.x + c4.y * h4.y + c4.z * h4.z + c4.w * h4.w;
        for (int off = 32; off; off >>= 1) v += __shfl_xor(v, off);
        if (lane == 0) attn_s[h] = v;
    }
    __syncthreads();

    // Wave-parallel top-10 (wave 0): lane owns h=lane and h=lane+64
    if (wave == 0) {
        float v0 = attn_s[lane];
        float v1 = (lane + 64 < NHIS) ? attn_s[lane + 64] : NEG_INF;
#pragma unroll
        for (int k = 0; k < NK; ++k) {
            float lv; int li;
            if (v1 > v0) { lv = v1; li = lane + 64; }
            else         { lv = v0; li = lane; }            // tie -> lower idx
            for (int off = 1; off < 64; off <<= 1) {
                const float ov = __shfl_xor(lv, off);
                const int   oi = __shfl_xor(li, off);
                if (ov > lv || (ov == lv && oi < li)) { lv = ov; li = oi; }
            }
            if (lane == 0) {
                const float w = (lv < THRESH) ? 0.0f : lv;
                const int g = bc * NK + k;
                ws_idx[g] = li;
                ws_w[g]   = w;
                out_idx_f[g] = (float)li;
            }
            if (li == lane)            v0 = NEG_INF;
            else if (li == lane + 64)  v1 = NEG_INF;
        }
    }
}

// ---------------------------------------------------------------------------
// Kernel 3: gather + scale. One block per (b,c,k).
//  - XCD-chunked block mapping: 3200 = 8*400, so each XCD owns 8 complete
//    b's; a b's unique read set (~3.7 MB) fits its 4 MB L2 -> duplicate
//    picks across cdds become L2 hits.
//  - w == 0 rows (attn < 0.1, ~45% of rows) are exact zeros in the
//    reference: skip the 92 KB source read entirely, just write zeros.
// ---------------------------------------------------------------------------
__global__ __launch_bounds__(256) void gather_kernel(
    const float* __restrict__ his_emb,
    const int* __restrict__ ws_idx,
    const float* __restrict__ ws_w,
    float* __restrict__ out)
{
    const int orig = blockIdx.x;
    const int g = (orig & 7) * 400 + (orig >> 3);   // XCD-chunked (bijective)
    const int b = g / (NCDD * NK);
    const int tid = threadIdx.x;
    const float w = ws_w[g];

    f32x4* __restrict__ dst = (f32x4*)(out + (size_t)g * TLD);

    if (w == 0.0f) {
        const f32x4 z = {0.f, 0.f, 0.f, 0.f};
#pragma unroll
        for (int it = 0; it < 22; ++it)
            __builtin_nontemporal_store(z, dst + tid + it * 256);
        if (tid < 128)
            __builtin_nontemporal_store(z, dst + 22 * 256 + tid);
        return;
    }

    const int idx = ws_idx[g];
    const f32x4* __restrict__ src =
        (const f32x4*)(his_emb + ((size_t)b * NHIS + idx) * TLD);

#pragma unroll 4
    for (int it = 0; it < 22; ++it) {
        const int i = tid + it * 256;
        f32x4 v = src[i];
        v *= w;
        __builtin_nontemporal_store(v, dst + i);
    }
    if (tid < 128) {
        const int i = 22 * 256 + tid;
        f32x4 v = src[i];
        v *= w;
        __builtin_nontemporal_store(v, dst + i);
    }
}

// ---------------------------------------------------------------------------
extern "C" void kernel_launch(void* const* d_in, const int* in_sizes, int n_in,
                              void* d_out, int out_size, void* d_ws, size_t ws_size,
                              hipStream_t stream)
{
    const float* cdd_repr = (const float*)d_in[0];   // (64,5,256)
    const float* his_repr = (const float*)d_in[1];   // (64,100,256)
    const float* his_emb  = (const float*)d_in[2];   // (64,100,30,3,256)
    const float* W_sel    = (const float*)d_in[3];   // (256,256)
    const float* b_sel    = (const float*)d_in[4];   // (256,)
    float* out = (float*)d_out;

    // Workspace layout
    char* ws = (char*)d_ws;
    float* his_p = (float*)(ws);                     // 6400*256*4 = 6,553,600 B
    int*   idx_i = (int*)  (ws + 6553600);           // 3200*4
    float* w_w   = (float*)(ws + 6566400);           // 3200*4

    // Output: his_activated [73,728,000] then idx [3200] (as float values)
    float* out_idx_f = out + (size_t)NB * NCDD * NK * TLD;

    proj_norm_kernel<<<(NB * NHIS) / 16, 256, 0, stream>>>(his_repr, W_sel, b_sel, his_p);
    cdd_attn_topk_kernel<<<NB * NCDD, 256, 0, stream>>>(cdd_repr, W_sel, b_sel,
                                                        his_p, out_idx_f, idx_i, w_w);
    gather_kernel<<<NB * NCDD * NK, 256, 0, stream>>>(his_emb, idx_i, w_w, out);
}

// Round 4
// 176.641 us; speedup vs baseline: 1.5077x; 1.0146x over previous
//
#include <hip/hip_runtime.h>
#include <hip/hip_bf16.h>

// Problem constants
#define NB   64
#define NCDD 5
#define NHIS 100
#define ND   256
#define NK   10
#define TLD  23040          // T*L*D = 30*3*256
#define THRESH 0.1f
#define NEG_INF (-3.402823466e38f)
#define NROWS_HIS 6400      // 64*100
#define NROWS_CDD 320       // 64*5

typedef float f32x4 __attribute__((ext_vector_type(4)));

// ---------------------------------------------------------------------------
// Kernel 1: projection + L2-norm for ALL rows (his rows 0..6399, cdd rows
// 6400..6719) in one launch. 16 rows per block; 6400 = 400*16 so blocks
// 0..399 are pure-his, 400..419 pure-cdd. X loads are lane-uniform -> scalar
// pipe; kernel is VALU-bound (~7 us).
// ---------------------------------------------------------------------------
__global__ __launch_bounds__(256) void proj_norm_all(
    const float* __restrict__ his_repr,
    const float* __restrict__ cdd_repr,
    const float* __restrict__ W,
    const float* __restrict__ bvec,
    float* __restrict__ Yall)
{
    __shared__ float red[4][16];
    const int r0  = blockIdx.x * 16;
    const int tid = threadIdx.x;

    const float* __restrict__ X = (r0 < NROWS_HIS)
        ? (his_repr + (size_t)r0 * ND)
        : (cdd_repr + (size_t)(r0 - NROWS_HIS) * ND);

    const float bias = bvec[tid];
    float acc[16];
#pragma unroll
    for (int r = 0; r < 16; ++r) acc[r] = bias;

    const float* wrow = W + (size_t)tid * ND;
    for (int k = 0; k < ND; k += 4) {
        const float4 w4 = *(const float4*)(wrow + k);
#pragma unroll
        for (int r = 0; r < 16; ++r) {
            const float4 x4 = *(const float4*)(X + (size_t)r * ND + k); // uniform -> s_load
            acc[r] += w4.x * x4.x + w4.y * x4.y + w4.z * x4.z + w4.w * x4.w;
        }
    }

    const int wave = tid >> 6, lane = tid & 63;
#pragma unroll
    for (int r = 0; r < 16; ++r) {
        float v = acc[r] * acc[r];
        for (int off = 32; off; off >>= 1) v += __shfl_xor(v, off);
        if (lane == 0) red[wave][r] = v;
    }
    __syncthreads();

#pragma unroll
    for (int r = 0; r < 16; ++r) {
        const float s = red[0][r] + red[1][r] + red[2][r] + red[3][r];
        const float scale = 1.0f / fmaxf(sqrtf(s), 1e-12f);
        Yall[(size_t)(r0 + r) * ND + tid] = acc[r] * scale;
    }
}

// ---------------------------------------------------------------------------
// Kernel 2: per (b,c) block — attn over 100 h, wave-parallel exact top-10
// (lax.top_k semantics: descending, lowest index on ties).
// ---------------------------------------------------------------------------
__global__ __launch_bounds__(256) void attn_topk_kernel(
    const float* __restrict__ cdd_p,
    const float* __restrict__ his_p,
    float* __restrict__ out_idx_f,
    int* __restrict__ ws_idx,
    float* __restrict__ ws_w)
{
    __shared__ float cvec[ND];
    __shared__ float attn_s[NHIS];
    const int bc  = blockIdx.x;            // b*NCDD + c
    const int b   = bc / NCDD;
    const int tid = threadIdx.x;
    const int wave = tid >> 6, lane = tid & 63;

    cvec[tid] = cdd_p[(size_t)bc * ND + tid];
    __syncthreads();

    const float4 c4 = ((const float4*)cvec)[lane];
    for (int h = wave; h < NHIS; h += 4) {
        const float4 h4 =
            ((const float4*)(his_p + ((size_t)b * NHIS + h) * ND))[lane];
        float v = c4.x * h4.x + c4.y * h4.y + c4.z * h4.z + c4.w * h4.w;
        for (int off = 32; off; off >>= 1) v += __shfl_xor(v, off);
        if (lane == 0) attn_s[h] = v;
    }
    __syncthreads();

    if (wave == 0) {
        float v0 = attn_s[lane];
        float v1 = (lane + 64 < NHIS) ? attn_s[lane + 64] : NEG_INF;
#pragma unroll
        for (int k = 0; k < NK; ++k) {
            float lv; int li;
            if (v1 > v0) { lv = v1; li = lane + 64; }
            else         { lv = v0; li = lane; }            // tie -> lower idx
            for (int off = 1; off < 64; off <<= 1) {
                const float ov = __shfl_xor(lv, off);
                const int   oi = __shfl_xor(li, off);
                if (ov > lv || (ov == lv && oi < li)) { lv = ov; li = oi; }
            }
            if (lane == 0) {
                const float w = (lv < THRESH) ? 0.0f : lv;
                const int g = bc * NK + k;
                ws_idx[g] = li;
                ws_w[g]   = w;
                out_idx_f[g] = (float)li;
            }
            if (li == lane)            v0 = NEG_INF;
            else if (li == lane + 64)  v1 = NEG_INF;
        }
    }
}

// ---------------------------------------------------------------------------
// Kernel 3: gather + scale. One block per (b,c,k). PLAIN stores (the m13
// float4-copy ubench that hits 6.29 TB/s mixed uses plain stores; NT stores
// are the prime suspect for the 2.7 TB/s we measured). Hand-batched 8-deep
// load->store groups for MLP. XCD-chunked mapping keeps each b's unique
// read set in one XCD's L2; w==0 rows skip the source read entirely.
// ---------------------------------------------------------------------------
__global__ __launch_bounds__(256) void gather_kernel(
    const float* __restrict__ his_emb,
    const int* __restrict__ ws_idx,
    const float* __restrict__ ws_w,
    float* __restrict__ out)
{
    const int orig = blockIdx.x;
    const int g = (orig & 7) * 400 + (orig >> 3);   // XCD-chunked (bijective)
    const int b = g / (NCDD * NK);
    const int tid = threadIdx.x;
    const float w = ws_w[g];

    f32x4* __restrict__ dst = (f32x4*)(out + (size_t)g * TLD);

    if (w == 0.0f) {
        const f32x4 z = {0.f, 0.f, 0.f, 0.f};
#pragma unroll
        for (int it = 0; it < 22; ++it) dst[tid + it * 256] = z;
        if (tid < 128) dst[22 * 256 + tid] = z;
        return;
    }

    const int idx = ws_idx[g];
    const f32x4* __restrict__ src =
        (const f32x4*)(his_emb + ((size_t)b * NHIS + idx) * TLD);

    f32x4 v[8];
#pragma unroll
    for (int j = 0; j < 8; ++j) v[j] = src[tid + j * 256];
#pragma unroll
    for (int j = 0; j < 8; ++j) dst[tid + j * 256] = v[j] * w;
#pragma unroll
    for (int j = 0; j < 8; ++j) v[j] = src[tid + (8 + j) * 256];
#pragma unroll
    for (int j = 0; j < 8; ++j) dst[tid + (8 + j) * 256] = v[j] * w;
#pragma unroll
    for (int j = 0; j < 6; ++j) v[j] = src[tid + (16 + j) * 256];
#pragma unroll
    for (int j = 0; j < 6; ++j) dst[tid + (16 + j) * 256] = v[j] * w;
    if (tid < 128) {
        const int i = 22 * 256 + tid;
        f32x4 t = src[i];
        dst[i] = t * w;
    }
}

// ---------------------------------------------------------------------------
extern "C" void kernel_launch(void* const* d_in, const int* in_sizes, int n_in,
                              void* d_out, int out_size, void* d_ws, size_t ws_size,
                              hipStream_t stream)
{
    const float* cdd_repr = (const float*)d_in[0];   // (64,5,256)
    const float* his_repr = (const float*)d_in[1];   // (64,100,256)
    const float* his_emb  = (const float*)d_in[2];   // (64,100,30,3,256)
    const float* W_sel    = (const float*)d_in[3];   // (256,256)
    const float* b_sel    = (const float*)d_in[4];   // (256,)
    float* out = (float*)d_out;

    // Workspace layout
    char* ws = (char*)d_ws;
    float* Yall  = (float*)ws;                       // 6720 rows * 256 * 4 = 6,881,280 B
    float* his_p = Yall;                             // rows [0, 6400)
    float* cdd_p = Yall + (size_t)NROWS_HIS * ND;    // rows [6400, 6720)
    int*   idx_i = (int*)  (ws + 6881280);           // 3200*4
    float* w_w   = (float*)(ws + 6894080);           // 3200*4

    // Output: his_activated [73,728,000] then idx [3200] (as float values)
    float* out_idx_f = out + (size_t)NB * NCDD * NK * TLD;

    proj_norm_all<<<(NROWS_HIS + NROWS_CDD) / 16, 256, 0, stream>>>(
        his_repr, cdd_repr, W_sel, b_sel, Yall);
    attn_topk_kernel<<<NB * NCDD, 256, 0, stream>>>(cdd_p, his_p,
                                                    out_idx_f, idx_i, w_w);
    gather_kernel<<<NB * NCDD * NK, 256, 0, stream>>>(his_emb, idx_i, w_w, out);
}

// Round 5
// 173.350 us; speedup vs baseline: 1.5364x; 1.0190x over previous
//
#include <hip/hip_runtime.h>
#include <hip/hip_bf16.h>

// Problem constants
#define NB   64
#define NCDD 5
#define NHIS 100
#define ND   256
#define NK   10
#define TLD  23040          // T*L*D = 30*3*256
#define THRESH 0.1f
#define NEG_INF (-3.402823466e38f)
#define NROWS_HIS 6400      // 64*100
#define NROWS_CDD 320       // 64*5

typedef float f32x4 __attribute__((ext_vector_type(4)));

// ---------------------------------------------------------------------------
// Kernel 1: projection + L2-norm for all 6720 rows. 8 rows/block -> 840
// blocks (3.3 blocks/CU) for latency hiding; X loads lane-uniform (scalar
// pipe), W row per thread streams from L2.
// ---------------------------------------------------------------------------
__global__ __launch_bounds__(256) void proj_norm_all(
    const float* __restrict__ his_repr,
    const float* __restrict__ cdd_repr,
    const float* __restrict__ W,
    const float* __restrict__ bvec,
    float* __restrict__ Yall)
{
    __shared__ float red[4][8];
    const int r0  = blockIdx.x * 8;
    const int tid = threadIdx.x;

    const float* __restrict__ X = (r0 < NROWS_HIS)
        ? (his_repr + (size_t)r0 * ND)
        : (cdd_repr + (size_t)(r0 - NROWS_HIS) * ND);

    const float bias = bvec[tid];
    float acc[8];
#pragma unroll
    for (int r = 0; r < 8; ++r) acc[r] = bias;

    const float* wrow = W + (size_t)tid * ND;
    for (int k = 0; k < ND; k += 4) {
        const float4 w4 = *(const float4*)(wrow + k);
#pragma unroll
        for (int r = 0; r < 8; ++r) {
            const float4 x4 = *(const float4*)(X + (size_t)r * ND + k); // uniform
            acc[r] += w4.x * x4.x + w4.y * x4.y + w4.z * x4.z + w4.w * x4.w;
        }
    }

    const int wave = tid >> 6, lane = tid & 63;
#pragma unroll
    for (int r = 0; r < 8; ++r) {
        float v = acc[r] * acc[r];
        for (int off = 32; off; off >>= 1) v += __shfl_xor(v, off);
        if (lane == 0) red[wave][r] = v;
    }
    __syncthreads();

#pragma unroll
    for (int r = 0; r < 8; ++r) {
        const float s = red[0][r] + red[1][r] + red[2][r] + red[3][r];
        const float scale = 1.0f / fmaxf(sqrtf(s), 1e-12f);
        Yall[(size_t)(r0 + r) * ND + tid] = acc[r] * scale;
    }
}

// ---------------------------------------------------------------------------
// Kernel 2: one block per b (512 threads). Threads 0..499 <-> (c,h) compute
// attn[c][h] = dot(cdd_p[b,c], his_p[b,h]) as independent per-thread dots
// (no shuffles, 4 partial accumulators for ILP, 8-deep unroll for MLP).
// cdd rows staged in LDS (<=2 distinct rows per wave -> broadcast, free).
// Then 5 waves run the 10-round argmax butterfly, one c each (lax.top_k
// semantics: descending, lowest index on ties).
// ---------------------------------------------------------------------------
__global__ __launch_bounds__(512) void attn_topk_kernel(
    const float* __restrict__ cdd_p,
    const float* __restrict__ his_p,
    float* __restrict__ out_idx_f,
    int* __restrict__ ws_idx,
    float* __restrict__ ws_w)
{
    __shared__ f32x4 cdds[NCDD * 64];        // 5 rows * 1 KB
    __shared__ float attn_s[NCDD][128];      // padded
    const int b   = blockIdx.x;
    const int tid = threadIdx.x;

    for (int i = tid; i < NCDD * 64; i += 512)
        cdds[i] = ((const f32x4*)(cdd_p + (size_t)b * NCDD * ND))[i];
    __syncthreads();

    if (tid < NCDD * NHIS) {
        const int c = tid / NHIS, h = tid % NHIS;
        const f32x4* __restrict__ hrow =
            (const f32x4*)(his_p + ((size_t)b * NHIS + h) * ND);
        float a0 = 0.f, a1 = 0.f, a2 = 0.f, a3 = 0.f;
#pragma unroll 8
        for (int k = 0; k < 64; k += 4) {
            const f32x4 c0 = cdds[c * 64 + k],     h0 = hrow[k];
            const f32x4 c1 = cdds[c * 64 + k + 1], h1 = hrow[k + 1];
            const f32x4 c2 = cdds[c * 64 + k + 2], h2 = hrow[k + 2];
            const f32x4 c3 = cdds[c * 64 + k + 3], h3 = hrow[k + 3];
            a0 += c0[0]*h0[0] + c0[1]*h0[1] + c0[2]*h0[2] + c0[3]*h0[3];
            a1 += c1[0]*h1[0] + c1[1]*h1[1] + c1[2]*h1[2] + c1[3]*h1[3];
            a2 += c2[0]*h2[0] + c2[1]*h2[1] + c2[2]*h2[2] + c2[3]*h2[3];
            a3 += c3[0]*h3[0] + c3[1]*h3[1] + c3[2]*h3[2] + c3[3]*h3[3];
        }
        attn_s[c][h] = (a0 + a1) + (a2 + a3);
    }
    __syncthreads();

    const int wave = tid >> 6, lane = tid & 63;
    if (wave < NCDD) {
        const int c = wave;
        float v0 = attn_s[c][lane];
        float v1 = (lane + 64 < NHIS) ? attn_s[c][lane + 64] : NEG_INF;
#pragma unroll
        for (int k = 0; k < NK; ++k) {
            float lv; int li;
            if (v1 > v0) { lv = v1; li = lane + 64; }
            else         { lv = v0; li = lane; }            // tie -> lower idx
            for (int off = 1; off < 64; off <<= 1) {
                const float ov = __shfl_xor(lv, off);
                const int   oi = __shfl_xor(li, off);
                if (ov > lv || (ov == lv && oi < li)) { lv = ov; li = oi; }
            }
            if (lane == 0) {
                const float w = (lv < THRESH) ? 0.0f : lv;
                const int g = (b * NCDD + c) * NK + k;
                ws_idx[g] = li;
                ws_w[g]   = w;
                out_idx_f[g] = (float)li;
            }
            if (li == lane)            v0 = NEG_INF;
            else if (li == lane + 64)  v1 = NEG_INF;
        }
    }
}

// ---------------------------------------------------------------------------
// Kernel 3: gather + scale — BYTE-IDENTICAL to R4 (attribution control).
// ---------------------------------------------------------------------------
__global__ __launch_bounds__(256) void gather_kernel(
    const float* __restrict__ his_emb,
    const int* __restrict__ ws_idx,
    const float* __restrict__ ws_w,
    float* __restrict__ out)
{
    const int orig = blockIdx.x;
    const int g = (orig & 7) * 400 + (orig >> 3);   // XCD-chunked (bijective)
    const int b = g / (NCDD * NK);
    const int tid = threadIdx.x;
    const float w = ws_w[g];

    f32x4* __restrict__ dst = (f32x4*)(out + (size_t)g * TLD);

    if (w == 0.0f) {
        const f32x4 z = {0.f, 0.f, 0.f, 0.f};
#pragma unroll
        for (int it = 0; it < 22; ++it) dst[tid + it * 256] = z;
        if (tid < 128) dst[22 * 256 + tid] = z;
        return;
    }

    const int idx = ws_idx[g];
    const f32x4* __restrict__ src =
        (const f32x4*)(his_emb + ((size_t)b * NHIS + idx) * TLD);

    f32x4 v[8];
#pragma unroll
    for (int j = 0; j < 8; ++j) v[j] = src[tid + j * 256];
#pragma unroll
    for (int j = 0; j < 8; ++j) dst[tid + j * 256] = v[j] * w;
#pragma unroll
    for (int j = 0; j < 8; ++j) v[j] = src[tid + (8 + j) * 256];
#pragma unroll
    for (int j = 0; j < 8; ++j) dst[tid + (8 + j) * 256] = v[j] * w;
#pragma unroll
    for (int j = 0; j < 6; ++j) v[j] = src[tid + (16 + j) * 256];
#pragma unroll
    for (int j = 0; j < 6; ++j) dst[tid + (16 + j) * 256] = v[j] * w;
    if (tid < 128) {
        const int i = 22 * 256 + tid;
        f32x4 t = src[i];
        dst[i] = t * w;
    }
}

// ---------------------------------------------------------------------------
extern "C" void kernel_launch(void* const* d_in, const int* in_sizes, int n_in,
                              void* d_out, int out_size, void* d_ws, size_t ws_size,
                              hipStream_t stream)
{
    const float* cdd_repr = (const float*)d_in[0];   // (64,5,256)
    const float* his_repr = (const float*)d_in[1];   // (64,100,256)
    const float* his_emb  = (const float*)d_in[2];   // (64,100,30,3,256)
    const float* W_sel    = (const float*)d_in[3];   // (256,256)
    const float* b_sel    = (const float*)d_in[4];   // (256,)
    float* out = (float*)d_out;

    // Workspace layout
    char* ws = (char*)d_ws;
    float* Yall  = (float*)ws;                       // 6720 rows * 256 * 4 = 6,881,280 B
    float* his_p = Yall;                             // rows [0, 6400)
    float* cdd_p = Yall + (size_t)NROWS_HIS * ND;    // rows [6400, 6720)
    int*   idx_i = (int*)  (ws + 6881280);           // 3200*4
    float* w_w   = (float*)(ws + 6894080);           // 3200*4

    // Output: his_activated [73,728,000] then idx [3200] (as float values)
    float* out_idx_f = out + (size_t)NB * NCDD * NK * TLD;

    proj_norm_all<<<(NROWS_HIS + NROWS_CDD) / 8, 256, 0, stream>>>(
        his_repr, cdd_repr, W_sel, b_sel, Yall);
    attn_topk_kernel<<<NB, 512, 0, stream>>>(cdd_p, his_p,
                                             out_idx_f, idx_i, w_w);
    gather_kernel<<<NB * NCDD * NK, 256, 0, stream>>>(his_emb, idx_i, w_w, out);
}